// Round 6
// baseline (412.137 us; speedup 1.0000x reference)
//
#include <hip/hip_runtime.h>
#include <hip/hip_bf16.h>

// Model_39676907885326: out = softmax(causal(q)) @ e
//   e[i,j,l]  = sum_k in[i,j,k] * w[l,k,j]
//   attn[i,j,l] = softmax_{l<=j}( (sum_k in[i,j,k]) * w[i,j,l] / (0.5 + sum_l w[i,j,l]) )
//   out[i]    = attn[i] @ e[i]
//
// Pipeline (ws regions):
//   R0 [0, N3) bf16        : wt[j][l][k]  ->  et[i][l][m]
//   R1 [N3, 2*N3) bf16     : e[i][j][l]   ->  attn[i][j][m]
//   RS [2*N3 ..) fp32 N2   : rs[i][j] = sum_k in[i,j,k]   (written by k_e2)
//   kT -> k_e2(+rs) -> k_eT -> k_attn(rs) -> k_av2
//
// R6: k_e2/k_av2 use double-buffered LDS, stage-next-before-compute, counted
// vmcnt + raw s_barrier (T3/T4-minimal), setprio around MFMA (T5).

#define N 384
#define N2 (N * N)
#define BK 64
static const size_t N3 = (size_t)N * N * N;

typedef __attribute__((ext_vector_type(8))) short s16x8;
typedef __attribute__((ext_vector_type(4))) float f32x4;

#define AS1 __attribute__((address_space(1)))
#define AS3 __attribute__((address_space(3)))
__device__ __forceinline__ void gll16(const void* g, void* l) {
    __builtin_amdgcn_global_load_lds((const AS1 unsigned int*)g,
                                     (AS3 unsigned int*)l, 16, 0, 0);
}
#define WAITV4 asm volatile("s_waitcnt vmcnt(4)" ::: "memory")
#define WAITV0 asm volatile("s_waitcnt vmcnt(0)" ::: "memory")
#define WAITL0 asm volatile("s_waitcnt lgkmcnt(0)" ::: "memory")
#define BAR    __builtin_amdgcn_s_barrier()

__device__ __forceinline__ unsigned short f32_to_bf16(float f) {
    unsigned int u = __float_as_uint(f);
    u += 0x7FFFu + ((u >> 16) & 1u);
    return (unsigned short)(u >> 16);
}
__device__ __forceinline__ float bf16_to_f32(unsigned short h) {
    return __uint_as_float((unsigned int)h << 16);
}
__device__ __forceinline__ unsigned int pk2(float a, float b) {
    return (unsigned int)f32_to_bf16(a) | ((unsigned int)f32_to_bf16(b) << 16);
}

// ---------------------------------------------------------------------------
// kT: wt[j*N2 + r] = bf16(w[r*N + j]), r = l*N+k
// ---------------------------------------------------------------------------
__global__ __launch_bounds__(256) void kT(const float* __restrict__ w,
                                          unsigned short* __restrict__ wt) {
    __shared__ unsigned short tile[64][68];
    const int r0 = blockIdx.x * 64;
    const int j0 = blockIdx.y * 64;
    const int tx = threadIdx.x & 63;
    const int ty = threadIdx.x >> 6;
#pragma unroll
    for (int p = 0; p < 16; ++p) {
        const int r = ty * 16 + p;
        tile[r][tx] = f32_to_bf16(w[(size_t)(r0 + r) * N + j0 + tx]);
    }
    __syncthreads();
#pragma unroll
    for (int p = 0; p < 16; ++p) {
        const int jj = ty * 16 + p;
        wt[(size_t)(j0 + jj) * N2 + r0 + tx] = tile[tx][jj];
    }
}

// ---------------------------------------------------------------------------
// k_e2: per j: e[i0..i0+63, j, l0..l0+191] = in[i,j,:] . wt[j][l][:]
// 256 threads, dbuf LDS, pipelined: stage t+1 (ds_write A from prefetched
// regs + gll B), compute t, counted vmcnt + raw barrier.
// ---------------------------------------------------------------------------
__global__ __launch_bounds__(256, 2) void k_e2(const float* __restrict__ in,
                                               const unsigned short* __restrict__ wt,
                                               unsigned short* __restrict__ e,
                                               float* __restrict__ rs) {
    __shared__ union {
        struct { unsigned short A[2][64 * 64]; unsigned short B[2][192 * 64]; } s;
        unsigned short C[64 * 200];
    } sm;

    const int lin = blockIdx.x;               // 4608 = 8 * 576
    const int swz = (lin & 7) * 576 + (lin >> 3);
    const int j   = swz / 12;
    const int sub = swz % 12;
    const int i0  = (sub >> 1) * 64;
    const int l0  = (sub & 1) * 192;

    const int t = threadIdx.x, lane = t & 63, wv = t >> 6;
    const int fr = lane & 15, fx = lane >> 4;

    const int ra = t >> 2, ca = (t & 3) * 2;
    const float* Ab = in + (size_t)(i0 + ra) * N2 + (size_t)j * N + ca * 8;
    const int aswz0 = ra * 64 + (((ca + 0) ^ (ra & 7)) * 8);
    const int aswz1 = ra * 64 + (((ca + 1) ^ (ra & 7)) * 8);

    const unsigned short* Wj = wt + (size_t)j * N2 + (size_t)l0 * N;
    const int rb_off = lane >> 3;
    const int p8     = lane & 7;

    f32x4 acc[4][3];
#pragma unroll
    for (int m = 0; m < 4; ++m)
#pragma unroll
        for (int n = 0; n < 3; ++n) acc[m][n] = (f32x4){0.f, 0.f, 0.f, 0.f};

    float rsum = 0.f;
    float4 va[4];

    // ---- prologue: tile 0 into buf0, prefetch va <- tile 1 ----
    va[0] = *(const float4*)(Ab);
    va[1] = *(const float4*)(Ab + 4);
    va[2] = *(const float4*)(Ab + 8);
    va[3] = *(const float4*)(Ab + 12);
#pragma unroll
    for (int itb = 0; itb < 6; ++itb) {
        const int rb = wv * 48 + itb * 8 + rb_off;
        const int sc = p8 ^ (rb & 7);
        gll16(Wj + (size_t)rb * N + sc * 8, sm.s.B[0] + (wv * 48 + itb * 8) * 64);
    }
    {
        rsum += (va[0].x + va[0].y + va[0].z + va[0].w) +
                (va[1].x + va[1].y + va[1].z + va[1].w) +
                (va[2].x + va[2].y + va[2].z + va[2].w) +
                (va[3].x + va[3].y + va[3].z + va[3].w);
        uint4 a0, a1;
        a0.x = pk2(va[0].x, va[0].y); a0.y = pk2(va[0].z, va[0].w);
        a0.z = pk2(va[1].x, va[1].y); a0.w = pk2(va[1].z, va[1].w);
        a1.x = pk2(va[2].x, va[2].y); a1.y = pk2(va[2].z, va[2].w);
        a1.z = pk2(va[3].x, va[3].y); a1.w = pk2(va[3].z, va[3].w);
        *(uint4*)(sm.s.A[0] + aswz0) = a0;
        *(uint4*)(sm.s.A[0] + aswz1) = a1;
    }
    va[0] = *(const float4*)(Ab + 64);
    va[1] = *(const float4*)(Ab + 68);
    va[2] = *(const float4*)(Ab + 72);
    va[3] = *(const float4*)(Ab + 76);
    WAITV4;   // retire tile-0 glls, leave va prefetch in flight
    WAITL0;
    BAR;

    // ---- main loop: tiles 0..5 ----
#pragma unroll
    for (int tt = 0; tt < 6; ++tt) {
        unsigned short* Ac = sm.s.A[tt & 1];
        unsigned short* An = sm.s.A[(tt + 1) & 1];
        unsigned short* Bc = sm.s.B[tt & 1];
        unsigned short* Bn = sm.s.B[(tt + 1) & 1];
        if (tt < 5) {
            const int kn = (tt + 1) * 64;
#pragma unroll
            for (int itb = 0; itb < 6; ++itb) {
                const int rb = wv * 48 + itb * 8 + rb_off;
                const int sc = p8 ^ (rb & 7);
                gll16(Wj + (size_t)rb * N + kn + sc * 8, Bn + (wv * 48 + itb * 8) * 64);
            }
            rsum += (va[0].x + va[0].y + va[0].z + va[0].w) +
                    (va[1].x + va[1].y + va[1].z + va[1].w) +
                    (va[2].x + va[2].y + va[2].z + va[2].w) +
                    (va[3].x + va[3].y + va[3].z + va[3].w);
            uint4 a0, a1;
            a0.x = pk2(va[0].x, va[0].y); a0.y = pk2(va[0].z, va[0].w);
            a0.z = pk2(va[1].x, va[1].y); a0.w = pk2(va[1].z, va[1].w);
            a1.x = pk2(va[2].x, va[2].y); a1.y = pk2(va[2].z, va[2].w);
            a1.z = pk2(va[3].x, va[3].y); a1.w = pk2(va[3].z, va[3].w);
            *(uint4*)(An + aswz0) = a0;
            *(uint4*)(An + aswz1) = a1;
        }
        if (tt < 4) {
            const float* Axn = Ab + (tt + 2) * 64;
            va[0] = *(const float4*)(Axn);
            va[1] = *(const float4*)(Axn + 4);
            va[2] = *(const float4*)(Axn + 8);
            va[3] = *(const float4*)(Axn + 12);
        }
        __builtin_amdgcn_s_setprio(1);
#pragma unroll
        for (int kk = 0; kk < 2; ++kk) {
            s16x8 af[4], bf[3];
#pragma unroll
            for (int m = 0; m < 4; ++m) {
                const int row = m * 16 + fr;
                const int x   = (kk * 4 + fx) ^ (row & 7);
                af[m] = *(const s16x8*)(Ac + row * 64 + x * 8);
            }
#pragma unroll
            for (int n = 0; n < 3; ++n) {
                const int row = wv * 48 + n * 16 + fr;
                const int x   = (kk * 4 + fx) ^ (row & 7);
                bf[n] = *(const s16x8*)(Bc + row * 64 + x * 8);
            }
#pragma unroll
            for (int m = 0; m < 4; ++m)
#pragma unroll
                for (int n = 0; n < 3; ++n)
                    acc[m][n] = __builtin_amdgcn_mfma_f32_16x16x32_bf16(
                        af[m], bf[n], acc[m][n], 0, 0, 0);
        }
        __builtin_amdgcn_s_setprio(0);
        if (tt < 5) {
            if (tt < 4) { WAITV4; } else { WAITV0; }
            WAITL0;
            BAR;
        }
    }

    // fused row-sum
    rsum += __shfl_xor(rsum, 1, 64);
    rsum += __shfl_xor(rsum, 2, 64);
    if (rs != nullptr && l0 == 0 && (t & 3) == 0)
        rs[(size_t)(i0 + ra) * N + j] = rsum;

    // epilogue: assemble 64x192 bf16 in LDS, stream full lines
    __syncthreads();
#pragma unroll
    for (int m = 0; m < 4; ++m)
#pragma unroll
        for (int n = 0; n < 3; ++n)
#pragma unroll
            for (int r = 0; r < 4; ++r)
                sm.C[(m * 16 + fx * 4 + r) * 200 + wv * 48 + n * 16 + fr] =
                    f32_to_bf16(acc[m][n][r]);
    __syncthreads();
#pragma unroll
    for (int it = 0; it < 6; ++it) {
        const int cid = it * 256 + t;
        const int row = cid / 24;
        const int c   = cid % 24;
        *(uint4*)(e + (size_t)(i0 + row) * N2 + (size_t)j * N + l0 + c * 8) =
            *(const uint4*)&sm.C[row * 200 + c * 8];
    }
}

// ---------------------------------------------------------------------------
// k_eT: et[i][l][m] = e[i][m][l]
// ---------------------------------------------------------------------------
__global__ __launch_bounds__(256) void k_eT(const unsigned short* __restrict__ e,
                                            unsigned short* __restrict__ et) {
    __shared__ unsigned short tile[64][68];
    const int m0 = blockIdx.x * 64, l0 = blockIdx.y * 64;
    const size_t ib = (size_t)blockIdx.z * N2;
    const int t  = threadIdx.x;
    const int c4 = (t & 15) * 4, r = t >> 4;
#pragma unroll
    for (int p = 0; p < 4; ++p) {
        ushort4 v = *(const ushort4*)(e + ib + (size_t)(m0 + r + 16 * p) * N + l0 + c4);
        tile[c4 + 0][r + 16 * p] = v.x;
        tile[c4 + 1][r + 16 * p] = v.y;
        tile[c4 + 2][r + 16 * p] = v.z;
        tile[c4 + 3][r + 16 * p] = v.w;
    }
    __syncthreads();
#pragma unroll
    for (int p = 0; p < 4; ++p) {
        const int lr = r + 16 * p;
        ushort4 v = *(const ushort4*)&tile[lr][c4];
        *(ushort4*)(et + ib + (size_t)(l0 + lr) * N + m0 + c4) = v;
    }
}

// ---------------------------------------------------------------------------
// k_attn: one wave per row (i,j); rs precomputed by k_e2
// ---------------------------------------------------------------------------
template <bool HAVE_RS>
__global__ __launch_bounds__(256) void k_attn(const float* __restrict__ in,
                                              const float* __restrict__ w,
                                              const float* __restrict__ rs,
                                              unsigned short* __restrict__ attn) {
    const int row  = blockIdx.x * 4 + (threadIdx.x >> 6);
    const int lane = threadIdx.x & 63;
    const int jr   = row % N;

    const float2* wp = (const float2*)(w + (size_t)row * N);

    float2 wv[3];
    float rs_in = 0.f, rs_w = 0.f;
#pragma unroll
    for (int c = 0; c < 3; ++c) {
        wv[c] = wp[lane + 64 * c];
        rs_w += wv[c].x + wv[c].y;
    }
    if (HAVE_RS) {
#pragma unroll
        for (int s = 1; s < 64; s <<= 1) rs_w += __shfl_xor(rs_w, s, 64);
        rs_in = rs[row];
    } else {
        const float2* ip = (const float2*)(in + (size_t)row * N);
#pragma unroll
        for (int c = 0; c < 3; ++c) {
            float2 iv = ip[lane + 64 * c];
            rs_in += iv.x + iv.y;
        }
#pragma unroll
        for (int s = 1; s < 64; s <<= 1) {
            rs_in += __shfl_xor(rs_in, s, 64);
            rs_w  += __shfl_xor(rs_w, s, 64);
        }
    }
    const float scale = rs_in / (0.5f + rs_w);

    float2 q[3];
    float mx = -INFINITY;
#pragma unroll
    for (int c = 0; c < 3; ++c) {
        const int l = (lane + 64 * c) * 2;
        q[c].x = (l     <= jr) ? scale * wv[c].x : -INFINITY;
        q[c].y = (l + 1 <= jr) ? scale * wv[c].y : -INFINITY;
        mx = fmaxf(mx, fmaxf(q[c].x, q[c].y));
    }
#pragma unroll
    for (int s = 1; s < 64; s <<= 1) mx = fmaxf(mx, __shfl_xor(mx, s, 64));

    float2 p[3];
    float sum = 0.f;
#pragma unroll
    for (int c = 0; c < 3; ++c) {
        const int l = (lane + 64 * c) * 2;
        p[c].x = (l     <= jr) ? exp2f((q[c].x - mx) * 1.44269504f) : 0.f;
        p[c].y = (l + 1 <= jr) ? exp2f((q[c].y - mx) * 1.44269504f) : 0.f;
        sum += p[c].x + p[c].y;
    }
#pragma unroll
    for (int s = 1; s < 64; s <<= 1) sum += __shfl_xor(sum, s, 64);
    const float inv = 1.f / sum;
    unsigned int* ap = (unsigned int*)(attn + (size_t)row * N);
#pragma unroll
    for (int c = 0; c < 3; ++c)
        ap[lane + 64 * c] = pk2(p[c].x * inv, p[c].y * inv);
}

// ---------------------------------------------------------------------------
// k_av2: per i: out[j0..j0+63, l0..l0+191] = attn[i] @ et[i]^T, K <= j0+64
// dbuf + pipelined gll staging (A and B both gll).
// ---------------------------------------------------------------------------
__global__ __launch_bounds__(256, 2) void k_av2(const unsigned short* __restrict__ attn,
                                                const unsigned short* __restrict__ et,
                                                float* __restrict__ out) {
    __shared__ union {
        struct { unsigned short A[2][64 * 64]; unsigned short B[2][192 * 64]; } s;
        float C[32 * 196];
    } sm;

    const int lin = blockIdx.x;
    const int swz = (lin & 7) * 576 + (lin >> 3);
    const int i   = swz / 12;
    const int sub = swz % 12;
    const int j0  = (sub >> 1) * 64;
    const int l0  = (sub & 1) * 192;
    const int nt  = (j0 >> 6) + 1;   // K-tiles: 1..6

    const int t = threadIdx.x, lane = t & 63, wv = t >> 6;
    const int fr = lane & 15, fx = lane >> 4;
    const int rb_off = lane >> 3;
    const int p8     = lane & 7;

    const unsigned short* Ag = attn + (size_t)i * N2 + (size_t)j0 * N;
    const unsigned short* Bg = et + (size_t)i * N2 + (size_t)l0 * N;

    f32x4 acc[4][3];
#pragma unroll
    for (int m = 0; m < 4; ++m)
#pragma unroll
        for (int n = 0; n < 3; ++n) acc[m][n] = (f32x4){0.f, 0.f, 0.f, 0.f};

    unsigned short* Ac = sm.s.A[0];
    unsigned short* An = sm.s.A[1];
    unsigned short* Bc = sm.s.B[0];
    unsigned short* Bn = sm.s.B[1];

    // prologue: stage tile 0
#pragma unroll
    for (int ita = 0; ita < 2; ++ita) {
        const int rb = wv * 16 + ita * 8 + rb_off;
        const int sc = p8 ^ (rb & 7);
        gll16(Ag + (size_t)rb * N + sc * 8, Ac + (wv * 16 + ita * 8) * 64);
    }
#pragma unroll
    for (int itb = 0; itb < 6; ++itb) {
        const int rb = wv * 48 + itb * 8 + rb_off;
        const int sc = p8 ^ (rb & 7);
        gll16(Bg + (size_t)rb * N + sc * 8, Bc + (wv * 48 + itb * 8) * 64);
    }
    WAITV0;
    BAR;

    for (int tt = 0; tt < nt; ++tt) {
        if (tt + 1 < nt) {
            const int kn = (tt + 1) * 64;
#pragma unroll
            for (int ita = 0; ita < 2; ++ita) {
                const int rb = wv * 16 + ita * 8 + rb_off;
                const int sc = p8 ^ (rb & 7);
                gll16(Ag + (size_t)rb * N + kn + sc * 8, An + (wv * 16 + ita * 8) * 64);
            }
#pragma unroll
            for (int itb = 0; itb < 6; ++itb) {
                const int rb = wv * 48 + itb * 8 + rb_off;
                const int sc = p8 ^ (rb & 7);
                gll16(Bg + (size_t)rb * N + kn + sc * 8, Bn + (wv * 48 + itb * 8) * 64);
            }
        }
        __builtin_amdgcn_s_setprio(1);
#pragma unroll
        for (int kk = 0; kk < 2; ++kk) {
            s16x8 af[4], bf[3];
#pragma unroll
            for (int m = 0; m < 4; ++m) {
                const int row = m * 16 + fr;
                const int x   = (kk * 4 + fx) ^ (row & 7);
                af[m] = *(const s16x8*)(Ac + row * 64 + x * 8);
            }
#pragma unroll
            for (int n = 0; n < 3; ++n) {
                const int row = wv * 48 + n * 16 + fr;
                const int x   = (kk * 4 + fx) ^ (row & 7);
                bf[n] = *(const s16x8*)(Bc + row * 64 + x * 8);
            }
#pragma unroll
            for (int m = 0; m < 4; ++m)
#pragma unroll
                for (int n = 0; n < 3; ++n)
                    acc[m][n] = __builtin_amdgcn_mfma_f32_16x16x32_bf16(
                        af[m], bf[n], acc[m][n], 0, 0, 0);
        }
        __builtin_amdgcn_s_setprio(0);
        if (tt + 1 < nt) {
            WAITV0;
            BAR;
            unsigned short* tp;
            tp = Ac; Ac = An; An = tp;
            tp = Bc; Bc = Bn; Bn = tp;
        }
    }

    __syncthreads();
#pragma unroll
    for (int ph = 0; ph < 2; ++ph) {
#pragma unroll
        for (int mm = 0; mm < 2; ++mm)
#pragma unroll
            for (int n = 0; n < 3; ++n)
#pragma unroll
                for (int r = 0; r < 4; ++r)
                    sm.C[(mm * 16 + fx * 4 + r) * 196 + wv * 48 + n * 16 + fr] =
                        acc[ph * 2 + mm][n][r];
        __syncthreads();
#pragma unroll
        for (int it = 0; it < 6; ++it) {
            const int cid = it * 256 + t;
            const int row = cid / 48;
            const int c   = cid % 48;
            *(float4*)(out + (size_t)i * N2 + (size_t)(j0 + ph * 32 + row) * N + l0 + c * 4) =
                *(const float4*)&sm.C[row * 196 + c * 4];
        }
        if (ph == 0) __syncthreads();
    }
}

extern "C" void kernel_launch(void* const* d_in, const int* in_sizes, int n_in,
                              void* d_out, int out_size, void* d_ws, size_t ws_size,
                              hipStream_t stream) {
    const float* in = (const float*)d_in[0];
    const float* w  = (const float*)d_in[1];
    float* out      = (float*)d_out;

    unsigned short* r0 = (unsigned short*)d_ws;       // wt -> et
    unsigned short* r1 = (unsigned short*)d_ws + N3;  // e  -> attn
    const bool have_rs = ws_size >= 2 * N3 * sizeof(unsigned short) + (size_t)N2 * sizeof(float);
    float* rs = have_rs ? (float*)((unsigned short*)d_ws + 2 * N3) : nullptr;

    kT<<<dim3(N2 / 64, N / 64), 256, 0, stream>>>(w, r0);
    k_e2<<<dim3(4608), 256, 0, stream>>>(in, r0, r1, rs);
    k_eT<<<dim3(6, 6, N), 256, 0, stream>>>(r1, r0);
    if (have_rs)
        k_attn<true><<<dim3(N2 / 4), 256, 0, stream>>>(in, w, rs, r1);
    else
        k_attn<false><<<dim3(N2 / 4), 256, 0, stream>>>(in, w, nullptr, r1);
    k_av2<<<dim3(4608), 256, 0, stream>>>(r1, r0, out);
}